// Round 3
// baseline (3116.410 us; speedup 1.0000x reference)
//
#include <hip/hip_runtime.h>
#include <math.h>

#define NPTS   200000
#define CR     64
#define CR2    32

#define NSEG0      1382400
#define SUM123_ROW2 172800
#define SUM123_ROW3 230400
#define SUM123_ROWS 252000

#define TVSEG  1382400       // B*GZ2*GY2*GX2 = 2*16*180*240
#define GX2    240
#define GY2    180
#define GZ2    16

#define NBATCH 21600         // NSEG0 / 64

// VALU broadcast: readlane -> SGPR, no DS traffic
__device__ __forceinline__ float bcastf(float v, int l) {
    return __int_as_float(__builtin_amdgcn_readlane(__float_as_int(v), l));
}

__device__ __forceinline__ int lin_scale(int b, int x, int y, int z,
                                         int ps, int dx, int dy, int dz) {
    int qx = x / ps, qy = y / ps, qz = z / ps;
    return ((b * dx + qx) * dy + qy) * dz + qz;
}

__device__ __forceinline__ void seg_decode(int seg, int& l1, int& l2, int& l3) {
    int qz = seg & 15; int rest = seg >> 4;
    int qy = rest % 180; int rest2 = rest / 180;
    int qx = rest2 % 240; int bb = rest2 / 240;
    l1 = ((bb * 120 + (qx >> 1)) * 90 + (qy >> 1)) * 8 + (qz >> 1);
    l2 = ((bb *  80 + (qx / 3)) * 60 + (qy / 3)) * 6 + (qz / 3);
    l3 = ((bb *  60 + (qx >> 2)) * 45 + (qy >> 2)) * 4 + (qz >> 2);
}

// ---------------- K_redscat: reduced = relu(in @ W_red + b) fused with scatter-add ------
// Also builds the compact active-cell list: cnt atomicAdd returns old; old==0 -> first
// touch -> append cell to list0, record rank for k_pgmax's gather.
__global__ __launch_bounds__(256) void k_redscat(
        const float* __restrict__ in, const int* __restrict__ coords,
        const float* __restrict__ Wred, const float* __restrict__ bred,
        float* __restrict__ red, float* __restrict__ sum0,
        float* __restrict__ cnt, int* __restrict__ list0,
        int* __restrict__ listCount, int* __restrict__ rankArr) {
    __shared__ float Wl[CR * CR];
    for (int i = threadIdx.x; i < CR * CR; i += blockDim.x) Wl[i] = Wred[i];
    __syncthreads();
    int lane = threadIdx.x & 63;
    float bl = bred[lane];
    int wid  = blockIdx.x * 4 + (threadIdx.x >> 6);
    int nw   = gridDim.x * 4;
    for (int p = wid; p < NPTS / 2; p += nw) {
        int r0 = 2 * p, r1 = r0 + 1;
        float x0 = in[(size_t)r0 * CR + lane];
        float x1 = in[(size_t)r1 * CR + lane];
        float acc0 = bl, acc1 = bl;
#pragma unroll
        for (int k = 0; k < CR; ++k) {
            float w = Wl[k * CR + lane];
            acc0 += bcastf(x0, k) * w;
            acc1 += bcastf(x1, k) * w;
        }
        acc0 = fmaxf(acc0, 0.f); acc1 = fmaxf(acc1, 0.f);
        red[(size_t)r0 * CR + lane] = acc0;
        red[(size_t)r1 * CR + lane] = acc1;
        int4 c0 = ((const int4*)coords)[r0];
        int4 c1 = ((const int4*)coords)[r1];
        int l0a = lin_scale(c0.x, c0.y, c0.z, c0.w, 2, 240, 180, 16);
        int l0b = lin_scale(c1.x, c1.y, c1.z, c1.w, 2, 240, 180, 16);
        atomicAdd(&sum0[(size_t)l0a * CR + lane], acc0);
        atomicAdd(&sum0[(size_t)l0b * CR + lane], acc1);
        if (lane == 0) {
            float olda = atomicAdd(&cnt[l0a], 1.0f);
            if (olda == 0.f) {
                int idx = atomicAdd(listCount, 1);
                list0[idx] = l0a; rankArr[l0a] = idx;
            }
            float oldb = atomicAdd(&cnt[l0b], 1.0f);
            if (oldb == 0.f) {
                int idx = atomicAdd(listCount, 1);
                list0[idx] = l0b; rankArr[l0b] = idx;
            }
        }
    }
}

// ---------------- K_gatt: fused gather-sum + att matvec for scales 1-3 ----------------
__global__ __launch_bounds__(256) void k_gatt(
        const float* __restrict__ sum0, float* __restrict__ attbuf,
        const float* __restrict__ cnt,
        const float* __restrict__ fcW, const float* __restrict__ fcB) {
    __shared__ float sw[3 * CR * CR2];   // 24 KB: fcW scales 1..3
    for (int i = threadIdx.x; i < 3 * CR * CR2; i += blockDim.x)
        sw[i] = fcW[CR * CR2 + i];
    __syncthreads();
    int lane = threadIdx.x & 63;
    int d = lane & 31;
    int wid = blockIdx.x * 4 + (threadIdx.x >> 6);
    int nw  = gridDim.x * 4;
    for (int s = wid; s < SUM123_ROWS; s += nw) {
        int childLin = -1;
        const float* w; float bj;
        if (s < SUM123_ROW2) {
            // scale 1 (ps=4): dims 120x90x8, children 2x2x2 of ps=2 grid
            int qz = s & 7, t = s >> 3;
            int qy = t % 90, t2 = t / 90;
            int qx = t2 % 120, b = t2 / 120;
            if (lane < 8) {
                int i = (lane >> 2) & 1, j = (lane >> 1) & 1, k = lane & 1;
                childLin = ((b * 240 + 2 * qx + i) * 180 + 2 * qy + j) * 16 + 2 * qz + k;
            }
            w = sw; bj = fcB[1 * CR2 + d];
        } else if (s < SUM123_ROW3) {
            // scale 2 (ps=6): dims 80x60x6, children 3x3x3 (z clamped: 3*5+2 > 15)
            int s2 = s - SUM123_ROW2;
            int qz = s2 % 6, t = s2 / 6;
            int qy = t % 60, t2 = t / 60;
            int qx = t2 % 80, b = t2 / 80;
            if (lane < 27) {
                int i = lane / 9, j = (lane / 3) % 3, k = lane % 3;
                int cz = 3 * qz + k;
                if (cz < 16)
                    childLin = ((b * 240 + 3 * qx + i) * 180 + 3 * qy + j) * 16 + cz;
            }
            w = sw + 2048; bj = fcB[2 * CR2 + d];
        } else {
            // scale 3 (ps=8): dims 60x45x4, children 4x4x4 (exactly 64 lanes)
            int s3 = s - SUM123_ROW3;
            int qz = s3 & 3, t = s3 >> 2;
            int qy = t % 45, t2 = t / 45;
            int qx = t2 % 60, b = t2 / 60;
            int i = lane >> 4, j = (lane >> 2) & 3, k = lane & 3;
            childLin = ((b * 240 + 4 * qx + i) * 180 + 4 * qy + j) * 16 + 4 * qz + k;
            w = sw + 4096; bj = fcB[3 * CR2 + d];
        }
        float myc = (childLin >= 0) ? cnt[childLin] : 0.f;
        unsigned long long mask = __ballot(myc > 0.f);
        if (!mask) continue;                 // empty cell: never read downstream
        float ctot = myc;
        ctot += __shfl_xor(ctot, 1, 64);
        ctot += __shfl_xor(ctot, 2, 64);
        ctot += __shfl_xor(ctot, 4, 64);
        ctot += __shfl_xor(ctot, 8, 64);
        ctot += __shfl_xor(ctot, 16, 64);
        ctot += __shfl_xor(ctot, 32, 64);
        float acc = 0.f;
        while (mask) {
            int j = __ffsll((long long)mask) - 1; mask &= mask - 1;
            int cl = __builtin_amdgcn_readlane(childLin, j);
            acc += sum0[(size_t)cl * CR + lane];
        }
        float m = acc * (1.f / ctot);
        float p = bj;
#pragma unroll
        for (int k = 0; k < CR; ++k)
            p += bcastf(m, k) * w[k * CR2 + d];
        float att = fmaxf(p, 0.f);
        if (lane < 32) attbuf[(size_t)s * CR2 + lane] = att;
    }
}

// ---------------- K_att0z: list-driven att0 into compact att0c + zero the sum rows ------
// Runs AFTER k_gatt (last reader of raw sums). Leaves tv fully zero for k_pgmax's maxes.
__global__ __launch_bounds__(256) void k_att0z(
        float* __restrict__ tv, const float* __restrict__ cnt,
        const int* __restrict__ list0, const int* __restrict__ listCount,
        const float* __restrict__ fcW, const float* __restrict__ fcB,
        float* __restrict__ att0c) {
    __shared__ float sw[CR * CR2];       // 8 KB: fc_list_W[0]
    for (int i = threadIdx.x; i < CR * CR2; i += blockDim.x) sw[i] = fcW[i];
    __syncthreads();
    int lane = threadIdx.x & 63;
    int d = lane & 31;
    int h = lane >> 5;
    float b0 = fcB[d];
    int total = listCount[0];
    int ngroups = (total + 3) >> 2;
    int wid = blockIdx.x * 4 + (threadIdx.x >> 6);
    int nw  = gridDim.x * 4;
    for (int g = wid; g < ngroups; g += nw) {
        int r0 = 4 * g;
        int r1 = min(r0 + 1, total - 1);
        int r2 = min(r0 + 2, total - 1);
        int r3 = min(r0 + 3, total - 1);
        int s0 = list0[r0], s1 = list0[r1], s2 = list0[r2], s3 = list0[r3];
        float* row0 = tv + (size_t)s0 * CR;
        float* row1 = tv + (size_t)s1 * CR;
        float* row2 = tv + (size_t)s2 * CR;
        float* row3 = tv + (size_t)s3 * CR;
        float m0 = row0[lane] * (1.f / cnt[s0]);
        float m1 = row1[lane] * (1.f / cnt[s1]);
        float m2 = row2[lane] * (1.f / cnt[s2]);
        float m3 = row3[lane] * (1.f / cnt[s3]);
        float p0 = b0, p1 = b0, p2 = b0, p3 = b0;
#pragma unroll
        for (int k = 0; k < CR; ++k) {
            float wk = sw[k * CR2 + d];
            p0 += bcastf(m0, k) * wk;
            p1 += bcastf(m1, k) * wk;
            p2 += bcastf(m2, k) * wk;
            p3 += bcastf(m3, k) * wk;
        }
        float a0 = fmaxf(p0, 0.f), a1 = fmaxf(p1, 0.f);
        float a2 = fmaxf(p2, 0.f), a3 = fmaxf(p3, 0.f);
        // h=0 lanes write ranks r0,r1; h=1 lanes write r2,r3 (dup tail ranks: same value)
        att0c[(size_t)(h ? r2 : r0) * CR2 + d] = h ? a2 : a0;
        att0c[(size_t)(h ? r3 : r1) * CR2 + d] = h ? a3 : a1;
        // zero sum rows (dup tail rows: benign double-zero)
        row0[lane] = 0.f; row1[lane] = 0.f; row2[lane] = 0.f; row3[lane] = 0.f;
    }
}

// ---------------- K_mm: M = out_fc_W @ lo_W1[64:128]  (32x64) ----------------
__global__ __launch_bounds__(1024) void k_mm(
        const float* __restrict__ outW, const float* __restrict__ loW1,
        float* __restrict__ M) {
    int e = threadIdx.x + blockIdx.x * 1024;
    if (e >= 2048) return;
    int r = e >> 6, c = e & 63;
    float acc = 0.f;
#pragma unroll
    for (int k = 0; k < 64; ++k)
        acc += outW[r * 64 + k] * loW1[(64 + k) * 64 + c];
    M[e] = acc;
}

// ---------------- K_seg: list-driven per-segment chain into compact gc ----------------
__global__ __launch_bounds__(256) void k_seg(
        const int* __restrict__ list0, const int* __restrict__ listCount,
        const float* __restrict__ att0c, const float* __restrict__ attbuf,
        const float* __restrict__ fc_W, const float* __restrict__ fcsW,
        const float* __restrict__ fcsB, const float* __restrict__ M,
        float* __restrict__ gc) {
    __shared__ float s_fcZ[1024];    // fc_W (32x32)
    __shared__ float s_fcs[4096];    // fcsW (4x32x32)
    __shared__ float s_M[2048];      // M (32x64)
    for (int i = threadIdx.x; i < 1024; i += 256) s_fcZ[i]  = fc_W[i];
    for (int i = threadIdx.x; i < 4096; i += 256) s_fcs[i]  = fcsW[i];
    for (int i = threadIdx.x; i < 2048; i += 256) s_M[i]    = M[i];
    __syncthreads();

    int lane = threadIdx.x & 63;
    int d = lane & 31;
    int h = lane >> 5;
    float vbA = fcsB[(h ? 1 : 0) * CR2 + d];
    float vbB = fcsB[(h ? 3 : 2) * CR2 + d];
    const float* VA = s_fcs + (h ? 1 : 0) * 1024;
    const float* VB = s_fcs + (h ? 3 : 2) * 1024;

    int total = listCount[0];
    int ngroups = (total + 3) >> 2;
    int wid = blockIdx.x * 4 + (threadIdx.x >> 6);
    int nw  = gridDim.x * 4;
    for (int g = wid; g < ngroups; g += nw) {
        int r0 = 4 * g;
        int r1 = min(r0 + 1, total - 1);
        int r2 = min(r0 + 2, total - 1);
        int r3 = min(r0 + 3, total - 1);
        int seg0 = list0[r0], seg1 = list0[r1], seg2 = list0[r2], seg3 = list0[r3];

        int l1_0, l2_0, l3_0, l1_1, l2_1, l3_1;
        int l1_2, l2_2, l3_2, l1_3, l2_3, l3_3;
        seg_decode(seg0, l1_0, l2_0, l3_0);
        seg_decode(seg1, l1_1, l2_1, l3_1);
        seg_decode(seg2, l1_2, l2_2, l3_2);
        seg_decode(seg3, l1_3, l2_3, l3_3);

        float a0_0 = att0c[(size_t)r0 * CR2 + d];
        float a0_1 = att0c[(size_t)r1 * CR2 + d];
        float a0_2 = att0c[(size_t)r2 * CR2 + d];
        float a0_3 = att0c[(size_t)r3 * CR2 + d];
        float a1_0 = attbuf[(size_t)l1_0 * CR2 + d];
        float a2_0 = attbuf[(size_t)(SUM123_ROW2 + l2_0) * CR2 + d];
        float a3_0 = attbuf[(size_t)(SUM123_ROW3 + l3_0) * CR2 + d];
        float a1_1 = attbuf[(size_t)l1_1 * CR2 + d];
        float a2_1 = attbuf[(size_t)(SUM123_ROW2 + l2_1) * CR2 + d];
        float a3_1 = attbuf[(size_t)(SUM123_ROW3 + l3_1) * CR2 + d];
        float a1_2 = attbuf[(size_t)l1_2 * CR2 + d];
        float a2_2 = attbuf[(size_t)(SUM123_ROW2 + l2_2) * CR2 + d];
        float a3_2 = attbuf[(size_t)(SUM123_ROW3 + l3_2) * CR2 + d];
        float a1_3 = attbuf[(size_t)l1_3 * CR2 + d];
        float a2_3 = attbuf[(size_t)(SUM123_ROW2 + l2_3) * CR2 + d];
        float a3_3 = attbuf[(size_t)(SUM123_ROW3 + l3_3) * CR2 + d];

        float fS0 = a0_0 + a1_0 + a2_0 + a3_0;
        float fS1 = a0_1 + a1_1 + a2_1 + a3_1;
        float fS2 = a0_2 + a1_2 + a2_2 + a3_2;
        float fS3 = a0_3 + a1_3 + a2_3 + a3_3;

        // featZ = relu(featS @ fc_W)
        float z0 = 0.f, z1 = 0.f, z2 = 0.f, z3 = 0.f;
#pragma unroll
        for (int cc = 0; cc < CR2; ++cc) {
            float wz = s_fcZ[cc * CR2 + d];
            z0 += bcastf(fS0, cc) * wz;
            z1 += bcastf(fS1, cc) * wz;
            z2 += bcastf(fS2, cc) * wz;
            z3 += bcastf(fS3, cc) * wz;
        }
        float fZ0 = fmaxf(z0, 0.f), fZ1 = fmaxf(z1, 0.f);
        float fZ2 = fmaxf(z2, 0.f), fZ3 = fmaxf(z3, 0.f);

        // att_v, half h handles scales {h, 2+h}
        float avA0 = vbA, avA1 = vbA, avA2 = vbA, avA3 = vbA;
        float avB0 = vbB, avB1 = vbB, avB2 = vbB, avB3 = vbB;
#pragma unroll
        for (int cc = 0; cc < CR2; ++cc) {
            float wa = VA[cc * CR2 + d];
            float wb = VB[cc * CR2 + d];
            float f0 = bcastf(fZ0, cc), f1 = bcastf(fZ1, cc);
            float f2 = bcastf(fZ2, cc), f3 = bcastf(fZ3, cc);
            avA0 += f0 * wa; avB0 += f0 * wb;
            avA1 += f1 * wa; avB1 += f1 * wb;
            avA2 += f2 * wa; avB2 += f2 * wb;
            avA3 += f3 * wa; avB3 += f3 * wb;
        }
        avA0 = 1.f / (1.f + __expf(-avA0)); avB0 = 1.f / (1.f + __expf(-avB0));
        avA1 = 1.f / (1.f + __expf(-avA1)); avB1 = 1.f / (1.f + __expf(-avB1));
        avA2 = 1.f / (1.f + __expf(-avA2)); avB2 = 1.f / (1.f + __expf(-avB2));
        avA3 = 1.f / (1.f + __expf(-avA3)); avB3 = 1.f / (1.f + __expf(-avB3));

        float u0 = (h ? a1_0 : a0_0) * avA0 + (h ? a3_0 : a2_0) * avB0;
        float u1 = (h ? a1_1 : a0_1) * avA1 + (h ? a3_1 : a2_1) * avB1;
        float u2 = (h ? a1_2 : a0_2) * avA2 + (h ? a3_2 : a2_2) * avB2;
        float u3 = (h ? a1_3 : a0_3) * avA3 + (h ? a3_3 : a2_3) * avB3;
        float fI0 = u0 + __shfl_xor(u0, 32, 64);
        float fI1 = u1 + __shfl_xor(u1, 32, 64);
        float fI2 = u2 + __shfl_xor(u2, 32, 64);
        float fI3 = u3 + __shfl_xor(u3, 32, 64);

        // g = fI @ M (full 64-wide output)
        float g0 = 0.f, g1 = 0.f, g2 = 0.f, g3 = 0.f;
#pragma unroll
        for (int dd = 0; dd < CR2; ++dd) {
            float wm = s_M[dd * CR + lane];
            g0 += bcastf(fI0, dd) * wm;
            g1 += bcastf(fI1, dd) * wm;
            g2 += bcastf(fI2, dd) * wm;
            g3 += bcastf(fI3, dd) * wm;
        }
        gc[(size_t)r0 * CR + lane] = g0;
        gc[(size_t)r1 * CR + lane] = g1;
        gc[(size_t)r2 * CR + lane] = g2;
        gc[(size_t)r3 * CR + lane] = g3;
    }
}

// orderable-uint encoding for float max
__device__ __forceinline__ unsigned int fkey(float f) {
    unsigned int b = __float_as_uint(f);
    return (b & 0x80000000u) ? ~b : (b | 0x80000000u);
}

// ---------------- K_pgmax: proj to d_out fused with scatter-max into tv -------------
// tv is fully zero at this point (memset + k_att0z), so atomicMax is safe concurrently.
__global__ __launch_bounds__(256) void k_pgmax(
        const float* __restrict__ red, const float* __restrict__ gc,
        const int* __restrict__ rankArr,
        const int* __restrict__ coords, const int* __restrict__ inv,
        const int* __restrict__ bxyz,
        const float* __restrict__ loW1, const float* __restrict__ loW2,
        const float* __restrict__ lob2, float* __restrict__ outProj,
        float* __restrict__ outLin, unsigned int* __restrict__ tvKey,
        unsigned char* __restrict__ flags) {
    __shared__ float s_W1[4096];
    __shared__ float s_W2[4096];
    for (int i = threadIdx.x; i < 4096; i += 256) s_W1[i] = loW1[i];
    for (int i = threadIdx.x; i < 4096; i += 256) s_W2[i] = loW2[i];
    __syncthreads();

    int lane = threadIdx.x & 63;
    float lob = lob2[lane];
    int wid = blockIdx.x * 4 + (threadIdx.x >> 6);
    int nw  = gridDim.x * 4;
    for (int q = wid; q < NPTS / 4; q += nw) {
        int i0 = 4 * q, i1 = i0 + 1, i2 = i0 + 2, i3 = i0 + 3;
        int s0 = inv[i0], s1 = inv[i1], s2 = inv[i2], s3 = inv[i3];
        int4 c0 = ((const int4*)coords)[s0];
        int4 c1 = ((const int4*)coords)[s1];
        int4 c2 = ((const int4*)coords)[s2];
        int4 c3 = ((const int4*)coords)[s3];
        int l0 = lin_scale(c0.x, c0.y, c0.z, c0.w, 2, 240, 180, 16);
        int l1 = lin_scale(c1.x, c1.y, c1.z, c1.w, 2, 240, 180, 16);
        int l2 = lin_scale(c2.x, c2.y, c2.z, c2.w, 2, 240, 180, 16);
        int l3 = lin_scale(c3.x, c3.y, c3.z, c3.w, 2, 240, 180, 16);
        int rk0 = rankArr[l0], rk1 = rankArr[l1];
        int rk2 = rankArr[l2], rk3 = rankArr[l3];

        float x0 = red[(size_t)s0 * CR + lane];
        float x1 = red[(size_t)s1 * CR + lane];
        float x2 = red[(size_t)s2 * CR + lane];
        float x3 = red[(size_t)s3 * CR + lane];
        float h0 = gc[(size_t)rk0 * CR + lane];
        float h1 = gc[(size_t)rk1 * CR + lane];
        float h2 = gc[(size_t)rk2 * CR + lane];
        float h3 = gc[(size_t)rk3 * CR + lane];
#pragma unroll
        for (int k = 0; k < CR; ++k) {
            float w = s_W1[k * CR + lane];
            h0 += bcastf(x0, k) * w;
            h1 += bcastf(x1, k) * w;
            h2 += bcastf(x2, k) * w;
            h3 += bcastf(x3, k) * w;
        }
        h0 = fmaxf(h0, 0.f); h1 = fmaxf(h1, 0.f);
        h2 = fmaxf(h2, 0.f); h3 = fmaxf(h3, 0.f);

        float q0 = lob, q1 = lob, q2 = lob, q3 = lob;
#pragma unroll
        for (int k = 0; k < CR; ++k) {
            float w = s_W2[k * CR + lane];
            q0 += bcastf(h0, k) * w;
            q1 += bcastf(h1, k) * w;
            q2 += bcastf(h2, k) * w;
            q3 += bcastf(h3, k) * w;
        }
        outProj[(size_t)i0 * CR + lane] = q0;
        outProj[(size_t)i1 * CR + lane] = q1;
        outProj[(size_t)i2 * CR + lane] = q2;
        outProj[(size_t)i3 * CR + lane] = q3;

        // fused scatter-max
        int4 b0 = ((const int4*)bxyz)[i0];
        int4 b1 = ((const int4*)bxyz)[i1];
        int4 b2 = ((const int4*)bxyz)[i2];
        int4 b3 = ((const int4*)bxyz)[i3];
        int n0 = ((b0.x * GZ2 + b0.w) * GY2 + b0.z) * GX2 + b0.y;
        int n1 = ((b1.x * GZ2 + b1.w) * GY2 + b1.z) * GX2 + b1.y;
        int n2 = ((b2.x * GZ2 + b2.w) * GY2 + b2.z) * GX2 + b2.y;
        int n3 = ((b3.x * GZ2 + b3.w) * GY2 + b3.z) * GX2 + b3.y;
        if (lane == 0) {
            outLin[i0] = (float)n0; flags[n0] = 1;
            outLin[i1] = (float)n1; flags[n1] = 1;
            outLin[i2] = (float)n2; flags[n2] = 1;
            outLin[i3] = (float)n3; flags[n3] = 1;
        }
        atomicMax(&tvKey[(size_t)n0 * CR + lane], fkey(q0));
        atomicMax(&tvKey[(size_t)n1 * CR + lane], fkey(q1));
        atomicMax(&tvKey[(size_t)n2 * CR + lane], fkey(q2));
        atomicMax(&tvKey[(size_t)n3 * CR + lane], fkey(q3));
    }
}

// ---------------- K5: decode tv keys, flag-driven ----------------
__global__ __launch_bounds__(256) void k_fix(
        unsigned int* __restrict__ tv, const unsigned char* __restrict__ flags) {
    int lane = threadIdx.x & 63;
    int wid = blockIdx.x * 4 + (threadIdx.x >> 6);
    int nw  = gridDim.x * 4;
    for (int batch = wid; batch < NBATCH; batch += nw) {
        int base = batch * 64;
        unsigned char f = flags[base + lane];
        unsigned long long mask = __ballot(f != 0);
        while (mask) {
            int j = __ffsll((long long)mask) - 1; mask &= mask - 1;
            size_t idx = (size_t)(base + j) * CR + lane;
            unsigned int k = tv[idx];
            float v = (k == 0u) ? 0.f
                    : __uint_as_float((k & 0x80000000u) ? (k & 0x7FFFFFFFu) : ~k);
            ((float*)tv)[idx] = v;
        }
    }
}

extern "C" void kernel_launch(void* const* d_in, const int* in_sizes, int n_in,
                              void* d_out, int out_size, void* d_ws, size_t ws_size,
                              hipStream_t stream) {
    (void)in_sizes; (void)n_in; (void)out_size; (void)ws_size;
    const float* in_data = (const float*)d_in[0];
    const int*   coords  = (const int*)d_in[1];
    const int*   inv     = (const int*)d_in[2];
    const int*   bxyz    = (const int*)d_in[3];
    const float* W_red   = (const float*)d_in[4];
    const float* b_red   = (const float*)d_in[5];
    const float* fcW     = (const float*)d_in[6];
    const float* fcB     = (const float*)d_in[7];
    const float* fcsW    = (const float*)d_in[8];
    const float* fcsB    = (const float*)d_in[9];
    const float* fc_W    = (const float*)d_in[10];
    const float* outW    = (const float*)d_in[11];
    const float* loW1    = (const float*)d_in[12];
    const float* loW2    = (const float*)d_in[13];
    const float* lob2    = (const float*)d_in[14];

    float* outProj = (float*)d_out;
    float* tv      = outProj + (size_t)NPTS * CR;        // tv region (sum0 -> keys -> tv_fmap)
    float* outLin  = tv + (size_t)TVSEG * CR;

    float* ws_f   = (float*)d_ws;
    float* red    = ws_f;                                // NPTS*64           (51.2 MB)
    float* attbuf = red + (size_t)NPTS * CR;             // 252000*32         (32.3 MB)
    float* cnt    = attbuf + (size_t)SUM123_ROWS * CR2;  // NSEG0 floats      (5.5 MB)
    int*   listCount = (int*)(cnt + (size_t)NSEG0);      // 4 ints (memset with cnt)
    int*   rankArr   = listCount + 4;                    // NSEG0 ints        (5.5 MB)
    int*   list0     = rankArr + (size_t)NSEG0;          // NPTS ints         (0.8 MB)
    float* att0c  = (float*)(list0 + (size_t)NPTS);      // NPTS*32           (25.6 MB)
    float* gc     = att0c + (size_t)NPTS * CR2;          // NPTS*64           (51.2 MB)
    float* Mmat   = gc + (size_t)NPTS * CR;              // 2048
    unsigned char* flags = (unsigned char*)(Mmat + 2048);// TVSEG bytes       (1.4 MB)

    hipMemsetAsync(tv, 0, (size_t)TVSEG * CR * sizeof(float), stream);
    hipMemsetAsync(cnt, 0, ((size_t)NSEG0 + 4) * sizeof(float), stream);
    hipMemsetAsync(flags, 0, (size_t)TVSEG, stream);

    k_mm<<<2, 1024, 0, stream>>>(outW, loW1, Mmat);
    k_redscat<<<1024, 256, 0, stream>>>(in_data, coords, W_red, b_red,
                                        red, tv, cnt, list0, listCount, rankArr);
    k_gatt<<<2048, 256, 0, stream>>>(tv, attbuf, cnt, fcW, fcB);
    k_att0z<<<1024, 256, 0, stream>>>(tv, cnt, list0, listCount, fcW, fcB, att0c);
    k_seg<<<1024, 256, 0, stream>>>(list0, listCount, att0c, attbuf,
                                    fc_W, fcsW, fcsB, Mmat, gc);
    k_pgmax<<<1024, 256, 0, stream>>>(red, gc, rankArr, coords, inv, bxyz,
                                      loW1, loW2, lob2, outProj,
                                      outLin, (unsigned int*)tv, flags);
    k_fix<<<512, 256, 0, stream>>>((unsigned int*)tv, flags);
}

// Round 4
// 1042.838 us; speedup vs baseline: 2.9884x; 2.9884x over previous
//
#include <hip/hip_runtime.h>
#include <math.h>

#define NPTS   200000
#define CR     64
#define CR2    32

#define NSEG0      1382400
#define SUM123_ROW2 172800
#define SUM123_ROW3 230400
#define SUM123_ROWS 252000

#define TVSEG  1382400       // B*GZ2*GY2*GX2 = 2*16*180*240
#define GX2    240
#define GY2    180
#define GZ2    16

#define NBATCH 21600         // NSEG0 / 64

// VALU broadcast: readlane -> SGPR, no DS traffic
__device__ __forceinline__ float bcastf(float v, int l) {
    return __int_as_float(__builtin_amdgcn_readlane(__float_as_int(v), l));
}

__device__ __forceinline__ int lin_scale(int b, int x, int y, int z,
                                         int ps, int dx, int dy, int dz) {
    int qx = x / ps, qy = y / ps, qz = z / ps;
    return ((b * dx + qx) * dy + qy) * dz + qz;
}

__device__ __forceinline__ void seg_decode(int seg, int& l1, int& l2, int& l3) {
    int qz = seg & 15; int rest = seg >> 4;
    int qy = rest % 180; int rest2 = rest / 180;
    int qx = rest2 % 240; int bb = rest2 / 240;
    l1 = ((bb * 120 + (qx >> 1)) * 90 + (qy >> 1)) * 8 + (qz >> 1);
    l2 = ((bb *  80 + (qx / 3)) * 60 + (qy / 3)) * 6 + (qz / 3);
    l3 = ((bb *  60 + (qx >> 2)) * 45 + (qy >> 2)) * 4 + (qz >> 2);
}

// ---------------- K_redscat: reduced = relu(in @ W_red + b) fused with scatter-add ------
// Fire-and-forget atomics ONLY (no returned values -> no wave-wide vmcnt stalls).
__global__ __launch_bounds__(256) void k_redscat(
        const float* __restrict__ in, const int* __restrict__ coords,
        const float* __restrict__ Wred, const float* __restrict__ bred,
        float* __restrict__ red, float* __restrict__ sum0,
        float* __restrict__ cnt) {
    __shared__ float Wl[CR * CR];
    for (int i = threadIdx.x; i < CR * CR; i += blockDim.x) Wl[i] = Wred[i];
    __syncthreads();
    int lane = threadIdx.x & 63;
    float bl = bred[lane];
    int wid  = blockIdx.x * 4 + (threadIdx.x >> 6);
    int nw   = gridDim.x * 4;
    for (int p = wid; p < NPTS / 2; p += nw) {
        int r0 = 2 * p, r1 = r0 + 1;
        float x0 = in[(size_t)r0 * CR + lane];
        float x1 = in[(size_t)r1 * CR + lane];
        float acc0 = bl, acc1 = bl;
#pragma unroll
        for (int k = 0; k < CR; ++k) {
            float w = Wl[k * CR + lane];
            acc0 += bcastf(x0, k) * w;
            acc1 += bcastf(x1, k) * w;
        }
        acc0 = fmaxf(acc0, 0.f); acc1 = fmaxf(acc1, 0.f);
        red[(size_t)r0 * CR + lane] = acc0;
        red[(size_t)r1 * CR + lane] = acc1;
        int4 c0 = ((const int4*)coords)[r0];
        int4 c1 = ((const int4*)coords)[r1];
        int l0a = lin_scale(c0.x, c0.y, c0.z, c0.w, 2, 240, 180, 16);
        int l0b = lin_scale(c1.x, c1.y, c1.z, c1.w, 2, 240, 180, 16);
        atomicAdd(&sum0[(size_t)l0a * CR + lane], acc0);
        atomicAdd(&sum0[(size_t)l0b * CR + lane], acc1);
        if (lane == 0) {
            atomicAdd(&cnt[l0a], 1.0f);
            atomicAdd(&cnt[l0b], 1.0f);
        }
    }
}

// ---------------- K_buildlist: compact active-cell list from cnt, block-aggregated ------
// 270 blocks x 80 batches of 64 cells. One listCount atomic PER BLOCK (270 total).
__global__ __launch_bounds__(256) void k_buildlist(
        const float* __restrict__ cnt, int* __restrict__ list0,
        int* __restrict__ listCount, int* __restrict__ rankArr) {
    __shared__ int s_wavecnt[4];
    __shared__ int s_base;
    int lane = threadIdx.x & 63;
    int w = threadIdx.x >> 6;
    int batch0 = blockIdx.x * 80 + w * 20;   // 20 batches per wave
    // pass 1: count active cells in this wave's 20 batches
    int mycount = 0;
    for (int b = 0; b < 20; ++b) {
        float c = cnt[(batch0 + b) * 64 + lane];
        unsigned long long mask = __ballot(c > 0.f);
        mycount += __popcll(mask);
    }
    if (lane == 0) s_wavecnt[w] = mycount;
    __syncthreads();
    if (threadIdx.x == 0) {
        int tot = s_wavecnt[0] + s_wavecnt[1] + s_wavecnt[2] + s_wavecnt[3];
        s_base = atomicAdd(listCount, tot);
    }
    __syncthreads();
    int offset = s_base;
    for (int ww = 0; ww < w; ++ww) offset += s_wavecnt[ww];
    // pass 2: write compact entries (cnt re-read is L2-hot)
    for (int b = 0; b < 20; ++b) {
        int cell = (batch0 + b) * 64 + lane;
        float c = cnt[cell];
        unsigned long long mask = __ballot(c > 0.f);
        if (c > 0.f) {
            int my = offset + __popcll(mask & ((1ull << lane) - 1ull));
            list0[my] = cell;
            rankArr[cell] = my;
        }
        offset += __popcll(mask);
    }
}

// ---------------- K_gatt: fused gather-sum + att matvec for scales 1-3 ----------------
__global__ __launch_bounds__(256) void k_gatt(
        const float* __restrict__ sum0, float* __restrict__ attbuf,
        const float* __restrict__ cnt,
        const float* __restrict__ fcW, const float* __restrict__ fcB) {
    __shared__ float sw[3 * CR * CR2];   // 24 KB: fcW scales 1..3
    for (int i = threadIdx.x; i < 3 * CR * CR2; i += blockDim.x)
        sw[i] = fcW[CR * CR2 + i];
    __syncthreads();
    int lane = threadIdx.x & 63;
    int d = lane & 31;
    int wid = blockIdx.x * 4 + (threadIdx.x >> 6);
    int nw  = gridDim.x * 4;
    for (int s = wid; s < SUM123_ROWS; s += nw) {
        int childLin = -1;
        const float* w; float bj;
        if (s < SUM123_ROW2) {
            // scale 1 (ps=4): dims 120x90x8, children 2x2x2 of ps=2 grid
            int qz = s & 7, t = s >> 3;
            int qy = t % 90, t2 = t / 90;
            int qx = t2 % 120, b = t2 / 120;
            if (lane < 8) {
                int i = (lane >> 2) & 1, j = (lane >> 1) & 1, k = lane & 1;
                childLin = ((b * 240 + 2 * qx + i) * 180 + 2 * qy + j) * 16 + 2 * qz + k;
            }
            w = sw; bj = fcB[1 * CR2 + d];
        } else if (s < SUM123_ROW3) {
            // scale 2 (ps=6): dims 80x60x6, children 3x3x3 (z clamped: 3*5+2 > 15)
            int s2 = s - SUM123_ROW2;
            int qz = s2 % 6, t = s2 / 6;
            int qy = t % 60, t2 = t / 60;
            int qx = t2 % 80, b = t2 / 80;
            if (lane < 27) {
                int i = lane / 9, j = (lane / 3) % 3, k = lane % 3;
                int cz = 3 * qz + k;
                if (cz < 16)
                    childLin = ((b * 240 + 3 * qx + i) * 180 + 3 * qy + j) * 16 + cz;
            }
            w = sw + 2048; bj = fcB[2 * CR2 + d];
        } else {
            // scale 3 (ps=8): dims 60x45x4, children 4x4x4 (exactly 64 lanes)
            int s3 = s - SUM123_ROW3;
            int qz = s3 & 3, t = s3 >> 2;
            int qy = t % 45, t2 = t / 45;
            int qx = t2 % 60, b = t2 / 60;
            int i = lane >> 4, j = (lane >> 2) & 3, k = lane & 3;
            childLin = ((b * 240 + 4 * qx + i) * 180 + 4 * qy + j) * 16 + 4 * qz + k;
            w = sw + 4096; bj = fcB[3 * CR2 + d];
        }
        float myc = (childLin >= 0) ? cnt[childLin] : 0.f;
        unsigned long long mask = __ballot(myc > 0.f);
        if (!mask) continue;                 // empty cell: never read downstream
        float ctot = myc;
        ctot += __shfl_xor(ctot, 1, 64);
        ctot += __shfl_xor(ctot, 2, 64);
        ctot += __shfl_xor(ctot, 4, 64);
        ctot += __shfl_xor(ctot, 8, 64);
        ctot += __shfl_xor(ctot, 16, 64);
        ctot += __shfl_xor(ctot, 32, 64);
        float acc = 0.f;
        while (mask) {
            int j = __ffsll((long long)mask) - 1; mask &= mask - 1;
            int cl = __builtin_amdgcn_readlane(childLin, j);
            acc += sum0[(size_t)cl * CR + lane];
        }
        float m = acc * (1.f / ctot);
        float p = bj;
#pragma unroll
        for (int k = 0; k < CR; ++k)
            p += bcastf(m, k) * w[k * CR2 + d];
        float att = fmaxf(p, 0.f);
        if (lane < 32) attbuf[(size_t)s * CR2 + lane] = att;
    }
}

// ---------------- K_att0z: list-driven att0 into compact att0c + zero the sum rows ------
// Runs AFTER k_gatt (last reader of raw sums). Leaves tv fully zero for k_pgmax's maxes.
__global__ __launch_bounds__(256) void k_att0z(
        float* __restrict__ tv, const float* __restrict__ cnt,
        const int* __restrict__ list0, const int* __restrict__ listCount,
        const float* __restrict__ fcW, const float* __restrict__ fcB,
        float* __restrict__ att0c) {
    __shared__ float sw[CR * CR2];       // 8 KB: fc_list_W[0]
    for (int i = threadIdx.x; i < CR * CR2; i += blockDim.x) sw[i] = fcW[i];
    __syncthreads();
    int lane = threadIdx.x & 63;
    int d = lane & 31;
    int h = lane >> 5;
    float b0 = fcB[d];
    int total = listCount[0];
    int ngroups = (total + 3) >> 2;
    int wid = blockIdx.x * 4 + (threadIdx.x >> 6);
    int nw  = gridDim.x * 4;
    for (int g = wid; g < ngroups; g += nw) {
        int r0 = 4 * g;
        int r1 = min(r0 + 1, total - 1);
        int r2 = min(r0 + 2, total - 1);
        int r3 = min(r0 + 3, total - 1);
        int s0 = list0[r0], s1 = list0[r1], s2 = list0[r2], s3 = list0[r3];
        float* row0 = tv + (size_t)s0 * CR;
        float* row1 = tv + (size_t)s1 * CR;
        float* row2 = tv + (size_t)s2 * CR;
        float* row3 = tv + (size_t)s3 * CR;
        float m0 = row0[lane] * (1.f / cnt[s0]);
        float m1 = row1[lane] * (1.f / cnt[s1]);
        float m2 = row2[lane] * (1.f / cnt[s2]);
        float m3 = row3[lane] * (1.f / cnt[s3]);
        float p0 = b0, p1 = b0, p2 = b0, p3 = b0;
#pragma unroll
        for (int k = 0; k < CR; ++k) {
            float wk = sw[k * CR2 + d];
            p0 += bcastf(m0, k) * wk;
            p1 += bcastf(m1, k) * wk;
            p2 += bcastf(m2, k) * wk;
            p3 += bcastf(m3, k) * wk;
        }
        float a0 = fmaxf(p0, 0.f), a1 = fmaxf(p1, 0.f);
        float a2 = fmaxf(p2, 0.f), a3 = fmaxf(p3, 0.f);
        // h=0 lanes write ranks r0,r1; h=1 lanes write r2,r3 (dup tail ranks: same value)
        att0c[(size_t)(h ? r2 : r0) * CR2 + d] = h ? a2 : a0;
        att0c[(size_t)(h ? r3 : r1) * CR2 + d] = h ? a3 : a1;
        // zero sum rows (dup tail rows: benign double-zero)
        row0[lane] = 0.f; row1[lane] = 0.f; row2[lane] = 0.f; row3[lane] = 0.f;
    }
}

// ---------------- K_mm: M = out_fc_W @ lo_W1[64:128]  (32x64) ----------------
__global__ __launch_bounds__(1024) void k_mm(
        const float* __restrict__ outW, const float* __restrict__ loW1,
        float* __restrict__ M) {
    int e = threadIdx.x + blockIdx.x * 1024;
    if (e >= 2048) return;
    int r = e >> 6, c = e & 63;
    float acc = 0.f;
#pragma unroll
    for (int k = 0; k < 64; ++k)
        acc += outW[r * 64 + k] * loW1[(64 + k) * 64 + c];
    M[e] = acc;
}

// ---------------- K_seg: list-driven per-segment chain into compact gc ----------------
__global__ __launch_bounds__(256) void k_seg(
        const int* __restrict__ list0, const int* __restrict__ listCount,
        const float* __restrict__ att0c, const float* __restrict__ attbuf,
        const float* __restrict__ fc_W, const float* __restrict__ fcsW,
        const float* __restrict__ fcsB, const float* __restrict__ M,
        float* __restrict__ gc) {
    __shared__ float s_fcZ[1024];    // fc_W (32x32)
    __shared__ float s_fcs[4096];    // fcsW (4x32x32)
    __shared__ float s_M[2048];      // M (32x64)
    for (int i = threadIdx.x; i < 1024; i += 256) s_fcZ[i]  = fc_W[i];
    for (int i = threadIdx.x; i < 4096; i += 256) s_fcs[i]  = fcsW[i];
    for (int i = threadIdx.x; i < 2048; i += 256) s_M[i]    = M[i];
    __syncthreads();

    int lane = threadIdx.x & 63;
    int d = lane & 31;
    int h = lane >> 5;
    float vbA = fcsB[(h ? 1 : 0) * CR2 + d];
    float vbB = fcsB[(h ? 3 : 2) * CR2 + d];
    const float* VA = s_fcs + (h ? 1 : 0) * 1024;
    const float* VB = s_fcs + (h ? 3 : 2) * 1024;

    int total = listCount[0];
    int ngroups = (total + 3) >> 2;
    int wid = blockIdx.x * 4 + (threadIdx.x >> 6);
    int nw  = gridDim.x * 4;
    for (int g = wid; g < ngroups; g += nw) {
        int r0 = 4 * g;
        int r1 = min(r0 + 1, total - 1);
        int r2 = min(r0 + 2, total - 1);
        int r3 = min(r0 + 3, total - 1);
        int seg0 = list0[r0], seg1 = list0[r1], seg2 = list0[r2], seg3 = list0[r3];

        int l1_0, l2_0, l3_0, l1_1, l2_1, l3_1;
        int l1_2, l2_2, l3_2, l1_3, l2_3, l3_3;
        seg_decode(seg0, l1_0, l2_0, l3_0);
        seg_decode(seg1, l1_1, l2_1, l3_1);
        seg_decode(seg2, l1_2, l2_2, l3_2);
        seg_decode(seg3, l1_3, l2_3, l3_3);

        float a0_0 = att0c[(size_t)r0 * CR2 + d];
        float a0_1 = att0c[(size_t)r1 * CR2 + d];
        float a0_2 = att0c[(size_t)r2 * CR2 + d];
        float a0_3 = att0c[(size_t)r3 * CR2 + d];
        float a1_0 = attbuf[(size_t)l1_0 * CR2 + d];
        float a2_0 = attbuf[(size_t)(SUM123_ROW2 + l2_0) * CR2 + d];
        float a3_0 = attbuf[(size_t)(SUM123_ROW3 + l3_0) * CR2 + d];
        float a1_1 = attbuf[(size_t)l1_1 * CR2 + d];
        float a2_1 = attbuf[(size_t)(SUM123_ROW2 + l2_1) * CR2 + d];
        float a3_1 = attbuf[(size_t)(SUM123_ROW3 + l3_1) * CR2 + d];
        float a1_2 = attbuf[(size_t)l1_2 * CR2 + d];
        float a2_2 = attbuf[(size_t)(SUM123_ROW2 + l2_2) * CR2 + d];
        float a3_2 = attbuf[(size_t)(SUM123_ROW3 + l3_2) * CR2 + d];
        float a1_3 = attbuf[(size_t)l1_3 * CR2 + d];
        float a2_3 = attbuf[(size_t)(SUM123_ROW2 + l2_3) * CR2 + d];
        float a3_3 = attbuf[(size_t)(SUM123_ROW3 + l3_3) * CR2 + d];

        float fS0 = a0_0 + a1_0 + a2_0 + a3_0;
        float fS1 = a0_1 + a1_1 + a2_1 + a3_1;
        float fS2 = a0_2 + a1_2 + a2_2 + a3_2;
        float fS3 = a0_3 + a1_3 + a2_3 + a3_3;

        // featZ = relu(featS @ fc_W)
        float z0 = 0.f, z1 = 0.f, z2 = 0.f, z3 = 0.f;
#pragma unroll
        for (int cc = 0; cc < CR2; ++cc) {
            float wz = s_fcZ[cc * CR2 + d];
            z0 += bcastf(fS0, cc) * wz;
            z1 += bcastf(fS1, cc) * wz;
            z2 += bcastf(fS2, cc) * wz;
            z3 += bcastf(fS3, cc) * wz;
        }
        float fZ0 = fmaxf(z0, 0.f), fZ1 = fmaxf(z1, 0.f);
        float fZ2 = fmaxf(z2, 0.f), fZ3 = fmaxf(z3, 0.f);

        // att_v, half h handles scales {h, 2+h}
        float avA0 = vbA, avA1 = vbA, avA2 = vbA, avA3 = vbA;
        float avB0 = vbB, avB1 = vbB, avB2 = vbB, avB3 = vbB;
#pragma unroll
        for (int cc = 0; cc < CR2; ++cc) {
            float wa = VA[cc * CR2 + d];
            float wb = VB[cc * CR2 + d];
            float f0 = bcastf(fZ0, cc), f1 = bcastf(fZ1, cc);
            float f2 = bcastf(fZ2, cc), f3 = bcastf(fZ3, cc);
            avA0 += f0 * wa; avB0 += f0 * wb;
            avA1 += f1 * wa; avB1 += f1 * wb;
            avA2 += f2 * wa; avB2 += f2 * wb;
            avA3 += f3 * wa; avB3 += f3 * wb;
        }
        avA0 = 1.f / (1.f + __expf(-avA0)); avB0 = 1.f / (1.f + __expf(-avB0));
        avA1 = 1.f / (1.f + __expf(-avA1)); avB1 = 1.f / (1.f + __expf(-avB1));
        avA2 = 1.f / (1.f + __expf(-avA2)); avB2 = 1.f / (1.f + __expf(-avB2));
        avA3 = 1.f / (1.f + __expf(-avA3)); avB3 = 1.f / (1.f + __expf(-avB3));

        float u0 = (h ? a1_0 : a0_0) * avA0 + (h ? a3_0 : a2_0) * avB0;
        float u1 = (h ? a1_1 : a0_1) * avA1 + (h ? a3_1 : a2_1) * avB1;
        float u2 = (h ? a1_2 : a0_2) * avA2 + (h ? a3_2 : a2_2) * avB2;
        float u3 = (h ? a1_3 : a0_3) * avA3 + (h ? a3_3 : a2_3) * avB3;
        float fI0 = u0 + __shfl_xor(u0, 32, 64);
        float fI1 = u1 + __shfl_xor(u1, 32, 64);
        float fI2 = u2 + __shfl_xor(u2, 32, 64);
        float fI3 = u3 + __shfl_xor(u3, 32, 64);

        // g = fI @ M (full 64-wide output)
        float g0 = 0.f, g1 = 0.f, g2 = 0.f, g3 = 0.f;
#pragma unroll
        for (int dd = 0; dd < CR2; ++dd) {
            float wm = s_M[dd * CR + lane];
            g0 += bcastf(fI0, dd) * wm;
            g1 += bcastf(fI1, dd) * wm;
            g2 += bcastf(fI2, dd) * wm;
            g3 += bcastf(fI3, dd) * wm;
        }
        gc[(size_t)r0 * CR + lane] = g0;
        gc[(size_t)r1 * CR + lane] = g1;
        gc[(size_t)r2 * CR + lane] = g2;
        gc[(size_t)r3 * CR + lane] = g3;
    }
}

// orderable-uint encoding for float max
__device__ __forceinline__ unsigned int fkey(float f) {
    unsigned int b = __float_as_uint(f);
    return (b & 0x80000000u) ? ~b : (b | 0x80000000u);
}

// ---------------- K_pgmax: proj to d_out fused with scatter-max into tv -------------
// tv is fully zero at this point (memset + k_att0z), so atomicMax is safe concurrently.
__global__ __launch_bounds__(256) void k_pgmax(
        const float* __restrict__ red, const float* __restrict__ gc,
        const int* __restrict__ rankArr,
        const int* __restrict__ coords, const int* __restrict__ inv,
        const int* __restrict__ bxyz,
        const float* __restrict__ loW1, const float* __restrict__ loW2,
        const float* __restrict__ lob2, float* __restrict__ outProj,
        float* __restrict__ outLin, unsigned int* __restrict__ tvKey,
        unsigned char* __restrict__ flags) {
    __shared__ float s_W1[4096];
    __shared__ float s_W2[4096];
    for (int i = threadIdx.x; i < 4096; i += 256) s_W1[i] = loW1[i];
    for (int i = threadIdx.x; i < 4096; i += 256) s_W2[i] = loW2[i];
    __syncthreads();

    int lane = threadIdx.x & 63;
    float lob = lob2[lane];
    int wid = blockIdx.x * 4 + (threadIdx.x >> 6);
    int nw  = gridDim.x * 4;
    for (int q = wid; q < NPTS / 4; q += nw) {
        int i0 = 4 * q, i1 = i0 + 1, i2 = i0 + 2, i3 = i0 + 3;
        int s0 = inv[i0], s1 = inv[i1], s2 = inv[i2], s3 = inv[i3];
        int4 c0 = ((const int4*)coords)[s0];
        int4 c1 = ((const int4*)coords)[s1];
        int4 c2 = ((const int4*)coords)[s2];
        int4 c3 = ((const int4*)coords)[s3];
        int l0 = lin_scale(c0.x, c0.y, c0.z, c0.w, 2, 240, 180, 16);
        int l1 = lin_scale(c1.x, c1.y, c1.z, c1.w, 2, 240, 180, 16);
        int l2 = lin_scale(c2.x, c2.y, c2.z, c2.w, 2, 240, 180, 16);
        int l3 = lin_scale(c3.x, c3.y, c3.z, c3.w, 2, 240, 180, 16);
        int rk0 = rankArr[l0], rk1 = rankArr[l1];
        int rk2 = rankArr[l2], rk3 = rankArr[l3];

        float x0 = red[(size_t)s0 * CR + lane];
        float x1 = red[(size_t)s1 * CR + lane];
        float x2 = red[(size_t)s2 * CR + lane];
        float x3 = red[(size_t)s3 * CR + lane];
        float h0 = gc[(size_t)rk0 * CR + lane];
        float h1 = gc[(size_t)rk1 * CR + lane];
        float h2 = gc[(size_t)rk2 * CR + lane];
        float h3 = gc[(size_t)rk3 * CR + lane];
#pragma unroll
        for (int k = 0; k < CR; ++k) {
            float w = s_W1[k * CR + lane];
            h0 += bcastf(x0, k) * w;
            h1 += bcastf(x1, k) * w;
            h2 += bcastf(x2, k) * w;
            h3 += bcastf(x3, k) * w;
        }
        h0 = fmaxf(h0, 0.f); h1 = fmaxf(h1, 0.f);
        h2 = fmaxf(h2, 0.f); h3 = fmaxf(h3, 0.f);

        float q0 = lob, q1 = lob, q2 = lob, q3 = lob;
#pragma unroll
        for (int k = 0; k < CR; ++k) {
            float w = s_W2[k * CR + lane];
            q0 += bcastf(h0, k) * w;
            q1 += bcastf(h1, k) * w;
            q2 += bcastf(h2, k) * w;
            q3 += bcastf(h3, k) * w;
        }
        outProj[(size_t)i0 * CR + lane] = q0;
        outProj[(size_t)i1 * CR + lane] = q1;
        outProj[(size_t)i2 * CR + lane] = q2;
        outProj[(size_t)i3 * CR + lane] = q3;

        // fused scatter-max
        int4 b0 = ((const int4*)bxyz)[i0];
        int4 b1 = ((const int4*)bxyz)[i1];
        int4 b2 = ((const int4*)bxyz)[i2];
        int4 b3 = ((const int4*)bxyz)[i3];
        int n0 = ((b0.x * GZ2 + b0.w) * GY2 + b0.z) * GX2 + b0.y;
        int n1 = ((b1.x * GZ2 + b1.w) * GY2 + b1.z) * GX2 + b1.y;
        int n2 = ((b2.x * GZ2 + b2.w) * GY2 + b2.z) * GX2 + b2.y;
        int n3 = ((b3.x * GZ2 + b3.w) * GY2 + b3.z) * GX2 + b3.y;
        if (lane == 0) {
            outLin[i0] = (float)n0; flags[n0] = 1;
            outLin[i1] = (float)n1; flags[n1] = 1;
            outLin[i2] = (float)n2; flags[n2] = 1;
            outLin[i3] = (float)n3; flags[n3] = 1;
        }
        atomicMax(&tvKey[(size_t)n0 * CR + lane], fkey(q0));
        atomicMax(&tvKey[(size_t)n1 * CR + lane], fkey(q1));
        atomicMax(&tvKey[(size_t)n2 * CR + lane], fkey(q2));
        atomicMax(&tvKey[(size_t)n3 * CR + lane], fkey(q3));
    }
}

// ---------------- K5: decode tv keys, flag-driven ----------------
__global__ __launch_bounds__(256) void k_fix(
        unsigned int* __restrict__ tv, const unsigned char* __restrict__ flags) {
    int lane = threadIdx.x & 63;
    int wid = blockIdx.x * 4 + (threadIdx.x >> 6);
    int nw  = gridDim.x * 4;
    for (int batch = wid; batch < NBATCH; batch += nw) {
        int base = batch * 64;
        unsigned char f = flags[base + lane];
        unsigned long long mask = __ballot(f != 0);
        while (mask) {
            int j = __ffsll((long long)mask) - 1; mask &= mask - 1;
            size_t idx = (size_t)(base + j) * CR + lane;
            unsigned int k = tv[idx];
            float v = (k == 0u) ? 0.f
                    : __uint_as_float((k & 0x80000000u) ? (k & 0x7FFFFFFFu) : ~k);
            ((float*)tv)[idx] = v;
        }
    }
}

extern "C" void kernel_launch(void* const* d_in, const int* in_sizes, int n_in,
                              void* d_out, int out_size, void* d_ws, size_t ws_size,
                              hipStream_t stream) {
    (void)in_sizes; (void)n_in; (void)out_size; (void)ws_size;
    const float* in_data = (const float*)d_in[0];
    const int*   coords  = (const int*)d_in[1];
    const int*   inv     = (const int*)d_in[2];
    const int*   bxyz    = (const int*)d_in[3];
    const float* W_red   = (const float*)d_in[4];
    const float* b_red   = (const float*)d_in[5];
    const float* fcW     = (const float*)d_in[6];
    const float* fcB     = (const float*)d_in[7];
    const float* fcsW    = (const float*)d_in[8];
    const float* fcsB    = (const float*)d_in[9];
    const float* fc_W    = (const float*)d_in[10];
    const float* outW    = (const float*)d_in[11];
    const float* loW1    = (const float*)d_in[12];
    const float* loW2    = (const float*)d_in[13];
    const float* lob2    = (const float*)d_in[14];

    float* outProj = (float*)d_out;
    float* tv      = outProj + (size_t)NPTS * CR;        // tv region (sum0 -> keys -> tv_fmap)
    float* outLin  = tv + (size_t)TVSEG * CR;

    float* ws_f   = (float*)d_ws;
    float* red    = ws_f;                                // NPTS*64           (51.2 MB)
    float* attbuf = red + (size_t)NPTS * CR;             // 252000*32         (32.3 MB)
    float* cnt    = attbuf + (size_t)SUM123_ROWS * CR2;  // NSEG0 floats      (5.5 MB)
    int*   listCount = (int*)(cnt + (size_t)NSEG0);      // 4 ints (memset with cnt)
    int*   rankArr   = listCount + 4;                    // NSEG0 ints        (5.5 MB)
    int*   list0     = rankArr + (size_t)NSEG0;          // NPTS ints         (0.8 MB)
    float* att0c  = (float*)(list0 + (size_t)NPTS);      // NPTS*32           (25.6 MB)
    float* gc     = att0c + (size_t)NPTS * CR2;          // NPTS*64           (51.2 MB)
    float* Mmat   = gc + (size_t)NPTS * CR;              // 2048
    unsigned char* flags = (unsigned char*)(Mmat + 2048);// TVSEG bytes       (1.4 MB)

    hipMemsetAsync(tv, 0, (size_t)TVSEG * CR * sizeof(float), stream);
    hipMemsetAsync(cnt, 0, ((size_t)NSEG0 + 4) * sizeof(float), stream);
    hipMemsetAsync(flags, 0, (size_t)TVSEG, stream);

    k_mm<<<2, 1024, 0, stream>>>(outW, loW1, Mmat);
    k_redscat<<<2048, 256, 0, stream>>>(in_data, coords, W_red, b_red,
                                        red, tv, cnt);
    k_buildlist<<<270, 256, 0, stream>>>(cnt, list0, (int*)listCount, rankArr);
    k_gatt<<<2048, 256, 0, stream>>>(tv, attbuf, cnt, fcW, fcB);
    k_att0z<<<1024, 256, 0, stream>>>(tv, cnt, list0, (const int*)listCount, fcW, fcB, att0c);
    k_seg<<<1024, 256, 0, stream>>>(list0, (const int*)listCount, att0c, attbuf,
                                    fc_W, fcsW, fcsB, Mmat, gc);
    k_pgmax<<<1024, 256, 0, stream>>>(red, gc, rankArr, coords, inv, bxyz,
                                      loW1, loW2, lob2, outProj,
                                      outLin, (unsigned int*)tv, flags);
    k_fix<<<512, 256, 0, stream>>>((unsigned int*)tv, flags);
}

// Round 5
// 1004.869 us; speedup vs baseline: 3.1013x; 1.0378x over previous
//
#include <hip/hip_runtime.h>
#include <math.h>

#define NPTS   200000
#define CR     64
#define CR2    32

#define NSEG0      1382400
#define SUM123_ROW2 172800
#define SUM123_ROW3 230400
#define SUM123_ROWS 252000

#define TVSEG  1382400       // B*GZ2*GY2*GX2 = 2*16*180*240
#define GX2    240
#define GY2    180
#define GZ2    16

#define NBATCH 21600         // NSEG0 / 64

// VALU broadcast: readlane -> SGPR, no DS traffic
__device__ __forceinline__ float bcastf(float v, int l) {
    return __int_as_float(__builtin_amdgcn_readlane(__float_as_int(v), l));
}

__device__ __forceinline__ int lin_scale(int b, int x, int y, int z,
                                         int ps, int dx, int dy, int dz) {
    int qx = x / ps, qy = y / ps, qz = z / ps;
    return ((b * dx + qx) * dy + qy) * dz + qz;
}

__device__ __forceinline__ void seg_decode(int seg, int& l1, int& l2, int& l3) {
    int qz = seg & 15; int rest = seg >> 4;
    int qy = rest % 180; int rest2 = rest / 180;
    int qx = rest2 % 240; int bb = rest2 / 240;
    l1 = ((bb * 120 + (qx >> 1)) * 90 + (qy >> 1)) * 8 + (qz >> 1);
    l2 = ((bb *  80 + (qx / 3)) * 60 + (qy / 3)) * 6 + (qz / 3);
    l3 = ((bb *  60 + (qx >> 2)) * 45 + (qy >> 2)) * 4 + (qz >> 2);
}

// ---------------- K_redscat: reduced = relu(in @ W_red + b) fused with scatter-add ------
// Fire-and-forget atomics ONLY (no returned values -> no wave-wide vmcnt stalls).
__global__ __launch_bounds__(256) void k_redscat(
        const float* __restrict__ in, const int* __restrict__ coords,
        const float* __restrict__ Wred, const float* __restrict__ bred,
        float* __restrict__ red, float* __restrict__ sum0,
        float* __restrict__ cnt) {
    __shared__ float Wl[CR * CR];
    for (int i = threadIdx.x; i < CR * CR; i += blockDim.x) Wl[i] = Wred[i];
    __syncthreads();
    int lane = threadIdx.x & 63;
    float bl = bred[lane];
    int wid  = blockIdx.x * 4 + (threadIdx.x >> 6);
    int nw   = gridDim.x * 4;
    for (int p = wid; p < NPTS / 2; p += nw) {
        int r0 = 2 * p, r1 = r0 + 1;
        float x0 = in[(size_t)r0 * CR + lane];
        float x1 = in[(size_t)r1 * CR + lane];
        float acc0 = bl, acc1 = bl;
#pragma unroll
        for (int k = 0; k < CR; ++k) {
            float w = Wl[k * CR + lane];
            acc0 += bcastf(x0, k) * w;
            acc1 += bcastf(x1, k) * w;
        }
        acc0 = fmaxf(acc0, 0.f); acc1 = fmaxf(acc1, 0.f);
        red[(size_t)r0 * CR + lane] = acc0;
        red[(size_t)r1 * CR + lane] = acc1;
        int4 c0 = ((const int4*)coords)[r0];
        int4 c1 = ((const int4*)coords)[r1];
        int l0a = lin_scale(c0.x, c0.y, c0.z, c0.w, 2, 240, 180, 16);
        int l0b = lin_scale(c1.x, c1.y, c1.z, c1.w, 2, 240, 180, 16);
        atomicAdd(&sum0[(size_t)l0a * CR + lane], acc0);
        atomicAdd(&sum0[(size_t)l0b * CR + lane], acc1);
        if (lane == 0) {
            atomicAdd(&cnt[l0a], 1.0f);
            atomicAdd(&cnt[l0b], 1.0f);
        }
    }
}

// ---------------- K_buildlist (+fused k_mm): compact list + M = out_fc_W @ lo_W1[64:] ----
// Blocks 0..269: list build (80 batches of 64 cells each; ONE listCount atomic per block).
// Blocks 270..277: M (32x64) = out_fc_W (32x64) @ lo_W1[64:128] (64x64).
__global__ __launch_bounds__(256) void k_buildlist(
        const float* __restrict__ cnt, int* __restrict__ list0,
        int* __restrict__ listCount, int* __restrict__ rankArr,
        const float* __restrict__ outW, const float* __restrict__ loW1,
        float* __restrict__ M) {
    if (blockIdx.x >= 270) {
        int e = (blockIdx.x - 270) * 256 + threadIdx.x;
        if (e < 2048) {
            int r = e >> 6, c = e & 63;
            float acc = 0.f;
#pragma unroll
            for (int k = 0; k < 64; ++k)
                acc += outW[r * 64 + k] * loW1[(64 + k) * 64 + c];
            M[e] = acc;
        }
        return;
    }
    __shared__ int s_wavecnt[4];
    __shared__ int s_base;
    int lane = threadIdx.x & 63;
    int w = threadIdx.x >> 6;
    int batch0 = blockIdx.x * 80 + w * 20;   // 20 batches per wave
    // pass 1: count active cells in this wave's 20 batches
    int mycount = 0;
    for (int b = 0; b < 20; ++b) {
        float c = cnt[(batch0 + b) * 64 + lane];
        unsigned long long mask = __ballot(c > 0.f);
        mycount += __popcll(mask);
    }
    if (lane == 0) s_wavecnt[w] = mycount;
    __syncthreads();
    if (threadIdx.x == 0) {
        int tot = s_wavecnt[0] + s_wavecnt[1] + s_wavecnt[2] + s_wavecnt[3];
        s_base = atomicAdd(listCount, tot);
    }
    __syncthreads();
    int offset = s_base;
    for (int ww = 0; ww < w; ++ww) offset += s_wavecnt[ww];
    // pass 2: write compact entries (cnt re-read is L2-hot)
    for (int b = 0; b < 20; ++b) {
        int cell = (batch0 + b) * 64 + lane;
        float c = cnt[cell];
        unsigned long long mask = __ballot(c > 0.f);
        if (c > 0.f) {
            int my = offset + __popcll(mask & ((1ull << lane) - 1ull));
            list0[my] = cell;
            rankArr[cell] = my;
        }
        offset += __popcll(mask);
    }
}

// ---------------- K_gatt: fused gather-sum + att matvec for scales 1-3 ----------------
__global__ __launch_bounds__(256) void k_gatt(
        const float* __restrict__ sum0, float* __restrict__ attbuf,
        const float* __restrict__ cnt,
        const float* __restrict__ fcW, const float* __restrict__ fcB) {
    __shared__ float sw[3 * CR * CR2];   // 24 KB: fcW scales 1..3
    for (int i = threadIdx.x; i < 3 * CR * CR2; i += blockDim.x)
        sw[i] = fcW[CR * CR2 + i];
    __syncthreads();
    int lane = threadIdx.x & 63;
    int d = lane & 31;
    int wid = blockIdx.x * 4 + (threadIdx.x >> 6);
    int nw  = gridDim.x * 4;
    for (int s = wid; s < SUM123_ROWS; s += nw) {
        int childLin = -1;
        const float* w; float bj;
        if (s < SUM123_ROW2) {
            // scale 1 (ps=4): dims 120x90x8, children 2x2x2 of ps=2 grid
            int qz = s & 7, t = s >> 3;
            int qy = t % 90, t2 = t / 90;
            int qx = t2 % 120, b = t2 / 120;
            if (lane < 8) {
                int i = (lane >> 2) & 1, j = (lane >> 1) & 1, k = lane & 1;
                childLin = ((b * 240 + 2 * qx + i) * 180 + 2 * qy + j) * 16 + 2 * qz + k;
            }
            w = sw; bj = fcB[1 * CR2 + d];
        } else if (s < SUM123_ROW3) {
            // scale 2 (ps=6): dims 80x60x6, children 3x3x3 (z clamped: 3*5+2 > 15)
            int s2 = s - SUM123_ROW2;
            int qz = s2 % 6, t = s2 / 6;
            int qy = t % 60, t2 = t / 60;
            int qx = t2 % 80, b = t2 / 80;
            if (lane < 27) {
                int i = lane / 9, j = (lane / 3) % 3, k = lane % 3;
                int cz = 3 * qz + k;
                if (cz < 16)
                    childLin = ((b * 240 + 3 * qx + i) * 180 + 3 * qy + j) * 16 + cz;
            }
            w = sw + 2048; bj = fcB[2 * CR2 + d];
        } else {
            // scale 3 (ps=8): dims 60x45x4, children 4x4x4 (exactly 64 lanes)
            int s3 = s - SUM123_ROW3;
            int qz = s3 & 3, t = s3 >> 2;
            int qy = t % 45, t2 = t / 45;
            int qx = t2 % 60, b = t2 / 60;
            int i = lane >> 4, j = (lane >> 2) & 3, k = lane & 3;
            childLin = ((b * 240 + 4 * qx + i) * 180 + 4 * qy + j) * 16 + 4 * qz + k;
            w = sw + 4096; bj = fcB[3 * CR2 + d];
        }
        float myc = (childLin >= 0) ? cnt[childLin] : 0.f;
        unsigned long long mask = __ballot(myc > 0.f);
        if (!mask) continue;                 // empty cell: never read downstream
        float ctot = myc;
        ctot += __shfl_xor(ctot, 1, 64);
        ctot += __shfl_xor(ctot, 2, 64);
        ctot += __shfl_xor(ctot, 4, 64);
        ctot += __shfl_xor(ctot, 8, 64);
        ctot += __shfl_xor(ctot, 16, 64);
        ctot += __shfl_xor(ctot, 32, 64);
        float acc = 0.f;
        while (mask) {
            int j = __ffsll((long long)mask) - 1; mask &= mask - 1;
            int cl = __builtin_amdgcn_readlane(childLin, j);
            acc += sum0[(size_t)cl * CR + lane];
        }
        float m = acc * (1.f / ctot);
        float p = bj;
#pragma unroll
        for (int k = 0; k < CR; ++k)
            p += bcastf(m, k) * w[k * CR2 + d];
        float att = fmaxf(p, 0.f);
        if (lane < 32) attbuf[(size_t)s * CR2 + lane] = att;
    }
}

// ---------------- K_segf: fused att0 + per-segment chain, zeroes sum rows ----------------
// Runs AFTER k_gatt (last reader of raw sums). att0 computed in-register (all lanes hold
// p0..p3 d-duplicated), sum rows zeroed for k_pgmax's atomicMax, g written to compact gc.
__global__ __launch_bounds__(256) void k_segf(
        float* __restrict__ tv, const float* __restrict__ cnt,
        const int* __restrict__ list0, const int* __restrict__ listCount,
        const float* __restrict__ fcW, const float* __restrict__ fcB,
        const float* __restrict__ fc_W, const float* __restrict__ fcsW,
        const float* __restrict__ fcsB, const float* __restrict__ M,
        const float* __restrict__ attbuf, float* __restrict__ gc) {
    __shared__ float s_w0[2048];     // fc_list_W[0] (64x32)
    __shared__ float s_fcZ[1024];    // fc_W (32x32)
    __shared__ float s_fcs[4096];    // fcsW (4x32x32)
    __shared__ float s_M[2048];      // M (32x64)
    for (int i = threadIdx.x; i < 2048; i += 256) s_w0[i]  = fcW[i];
    for (int i = threadIdx.x; i < 1024; i += 256) s_fcZ[i] = fc_W[i];
    for (int i = threadIdx.x; i < 4096; i += 256) s_fcs[i] = fcsW[i];
    for (int i = threadIdx.x; i < 2048; i += 256) s_M[i]   = M[i];
    __syncthreads();

    int lane = threadIdx.x & 63;
    int d = lane & 31;
    int h = lane >> 5;
    float b0  = fcB[d];
    float vbA = fcsB[(h ? 1 : 0) * CR2 + d];
    float vbB = fcsB[(h ? 3 : 2) * CR2 + d];
    const float* VA = s_fcs + (h ? 1 : 0) * 1024;
    const float* VB = s_fcs + (h ? 3 : 2) * 1024;

    int total = listCount[0];
    int ngroups = (total + 3) >> 2;
    int wid = blockIdx.x * 4 + (threadIdx.x >> 6);
    int nw  = gridDim.x * 4;
    for (int g = wid; g < ngroups; g += nw) {
        int r0 = 4 * g;
        int r1 = min(r0 + 1, total - 1);
        int r2 = min(r0 + 2, total - 1);
        int r3 = min(r0 + 3, total - 1);
        int seg0 = list0[r0], seg1 = list0[r1], seg2 = list0[r2], seg3 = list0[r3];
        float* row0 = tv + (size_t)seg0 * CR;
        float* row1 = tv + (size_t)seg1 * CR;
        float* row2 = tv + (size_t)seg2 * CR;
        float* row3 = tv + (size_t)seg3 * CR;
        float m0 = row0[lane] * (1.f / cnt[seg0]);
        float m1 = row1[lane] * (1.f / cnt[seg1]);
        float m2 = row2[lane] * (1.f / cnt[seg2]);
        float m3 = row3[lane] * (1.f / cnt[seg3]);
        // zero sum rows now (reads done; dup tail rows double-zero benign)
        row0[lane] = 0.f; row1[lane] = 0.f; row2[lane] = 0.f; row3[lane] = 0.f;

        // att0 matvec (all lanes, d-duplicated across halves)
        float p0 = b0, p1 = b0, p2 = b0, p3 = b0;
#pragma unroll
        for (int k = 0; k < CR; ++k) {
            float wk = s_w0[k * CR2 + d];
            p0 += bcastf(m0, k) * wk;
            p1 += bcastf(m1, k) * wk;
            p2 += bcastf(m2, k) * wk;
            p3 += bcastf(m3, k) * wk;
        }
        float a0_0 = fmaxf(p0, 0.f), a0_1 = fmaxf(p1, 0.f);
        float a0_2 = fmaxf(p2, 0.f), a0_3 = fmaxf(p3, 0.f);

        int l1_0, l2_0, l3_0, l1_1, l2_1, l3_1;
        int l1_2, l2_2, l3_2, l1_3, l2_3, l3_3;
        seg_decode(seg0, l1_0, l2_0, l3_0);
        seg_decode(seg1, l1_1, l2_1, l3_1);
        seg_decode(seg2, l1_2, l2_2, l3_2);
        seg_decode(seg3, l1_3, l2_3, l3_3);

        float a1_0 = attbuf[(size_t)l1_0 * CR2 + d];
        float a2_0 = attbuf[(size_t)(SUM123_ROW2 + l2_0) * CR2 + d];
        float a3_0 = attbuf[(size_t)(SUM123_ROW3 + l3_0) * CR2 + d];
        float a1_1 = attbuf[(size_t)l1_1 * CR2 + d];
        float a2_1 = attbuf[(size_t)(SUM123_ROW2 + l2_1) * CR2 + d];
        float a3_1 = attbuf[(size_t)(SUM123_ROW3 + l3_1) * CR2 + d];
        float a1_2 = attbuf[(size_t)l1_2 * CR2 + d];
        float a2_2 = attbuf[(size_t)(SUM123_ROW2 + l2_2) * CR2 + d];
        float a3_2 = attbuf[(size_t)(SUM123_ROW3 + l3_2) * CR2 + d];
        float a1_3 = attbuf[(size_t)l1_3 * CR2 + d];
        float a2_3 = attbuf[(size_t)(SUM123_ROW2 + l2_3) * CR2 + d];
        float a3_3 = attbuf[(size_t)(SUM123_ROW3 + l3_3) * CR2 + d];

        float fS0 = a0_0 + a1_0 + a2_0 + a3_0;
        float fS1 = a0_1 + a1_1 + a2_1 + a3_1;
        float fS2 = a0_2 + a1_2 + a2_2 + a3_2;
        float fS3 = a0_3 + a1_3 + a2_3 + a3_3;

        // featZ = relu(featS @ fc_W)
        float z0 = 0.f, z1 = 0.f, z2 = 0.f, z3 = 0.f;
#pragma unroll
        for (int cc = 0; cc < CR2; ++cc) {
            float wz = s_fcZ[cc * CR2 + d];
            z0 += bcastf(fS0, cc) * wz;
            z1 += bcastf(fS1, cc) * wz;
            z2 += bcastf(fS2, cc) * wz;
            z3 += bcastf(fS3, cc) * wz;
        }
        float fZ0 = fmaxf(z0, 0.f), fZ1 = fmaxf(z1, 0.f);
        float fZ2 = fmaxf(z2, 0.f), fZ3 = fmaxf(z3, 0.f);

        // att_v, half h handles scales {h, 2+h}
        float avA0 = vbA, avA1 = vbA, avA2 = vbA, avA3 = vbA;
        float avB0 = vbB, avB1 = vbB, avB2 = vbB, avB3 = vbB;
#pragma unroll
        for (int cc = 0; cc < CR2; ++cc) {
            float wa = VA[cc * CR2 + d];
            float wb = VB[cc * CR2 + d];
            float f0 = bcastf(fZ0, cc), f1 = bcastf(fZ1, cc);
            float f2 = bcastf(fZ2, cc), f3 = bcastf(fZ3, cc);
            avA0 += f0 * wa; avB0 += f0 * wb;
            avA1 += f1 * wa; avB1 += f1 * wb;
            avA2 += f2 * wa; avB2 += f2 * wb;
            avA3 += f3 * wa; avB3 += f3 * wb;
        }
        avA0 = 1.f / (1.f + __expf(-avA0)); avB0 = 1.f / (1.f + __expf(-avB0));
        avA1 = 1.f / (1.f + __expf(-avA1)); avB1 = 1.f / (1.f + __expf(-avB1));
        avA2 = 1.f / (1.f + __expf(-avA2)); avB2 = 1.f / (1.f + __expf(-avB2));
        avA3 = 1.f / (1.f + __expf(-avA3)); avB3 = 1.f / (1.f + __expf(-avB3));

        float u0 = (h ? a1_0 : a0_0) * avA0 + (h ? a3_0 : a2_0) * avB0;
        float u1 = (h ? a1_1 : a0_1) * avA1 + (h ? a3_1 : a2_1) * avB1;
        float u2 = (h ? a1_2 : a0_2) * avA2 + (h ? a3_2 : a2_2) * avB2;
        float u3 = (h ? a1_3 : a0_3) * avA3 + (h ? a3_3 : a2_3) * avB3;
        float fI0 = u0 + __shfl_xor(u0, 32, 64);
        float fI1 = u1 + __shfl_xor(u1, 32, 64);
        float fI2 = u2 + __shfl_xor(u2, 32, 64);
        float fI3 = u3 + __shfl_xor(u3, 32, 64);

        // g = fI @ M (full 64-wide output)
        float g0 = 0.f, g1 = 0.f, g2 = 0.f, g3 = 0.f;
#pragma unroll
        for (int dd = 0; dd < CR2; ++dd) {
            float wm = s_M[dd * CR + lane];
            g0 += bcastf(fI0, dd) * wm;
            g1 += bcastf(fI1, dd) * wm;
            g2 += bcastf(fI2, dd) * wm;
            g3 += bcastf(fI3, dd) * wm;
        }
        gc[(size_t)r0 * CR + lane] = g0;
        gc[(size_t)r1 * CR + lane] = g1;
        gc[(size_t)r2 * CR + lane] = g2;
        gc[(size_t)r3 * CR + lane] = g3;
    }
}

// orderable-uint encoding for float max
__device__ __forceinline__ unsigned int fkey(float f) {
    unsigned int b = __float_as_uint(f);
    return (b & 0x80000000u) ? ~b : (b | 0x80000000u);
}

// ---------------- K_pgmax: proj to d_out fused with scatter-max into tv -------------
// tv is fully zero at this point (memset + k_segf), so atomicMax is safe concurrently.
__global__ __launch_bounds__(256) void k_pgmax(
        const float* __restrict__ red, const float* __restrict__ gc,
        const int* __restrict__ rankArr,
        const int* __restrict__ coords, const int* __restrict__ inv,
        const int* __restrict__ bxyz,
        const float* __restrict__ loW1, const float* __restrict__ loW2,
        const float* __restrict__ lob2, float* __restrict__ outProj,
        float* __restrict__ outLin, unsigned int* __restrict__ tvKey,
        unsigned char* __restrict__ flags) {
    __shared__ float s_W1[4096];
    __shared__ float s_W2[4096];
    for (int i = threadIdx.x; i < 4096; i += 256) s_W1[i] = loW1[i];
    for (int i = threadIdx.x; i < 4096; i += 256) s_W2[i] = loW2[i];
    __syncthreads();

    int lane = threadIdx.x & 63;
    float lob = lob2[lane];
    int wid = blockIdx.x * 4 + (threadIdx.x >> 6);
    int nw  = gridDim.x * 4;
    for (int q = wid; q < NPTS / 4; q += nw) {
        int i0 = 4 * q, i1 = i0 + 1, i2 = i0 + 2, i3 = i0 + 3;
        int s0 = inv[i0], s1 = inv[i1], s2 = inv[i2], s3 = inv[i3];
        int4 c0 = ((const int4*)coords)[s0];
        int4 c1 = ((const int4*)coords)[s1];
        int4 c2 = ((const int4*)coords)[s2];
        int4 c3 = ((const int4*)coords)[s3];
        int l0 = lin_scale(c0.x, c0.y, c0.z, c0.w, 2, 240, 180, 16);
        int l1 = lin_scale(c1.x, c1.y, c1.z, c1.w, 2, 240, 180, 16);
        int l2 = lin_scale(c2.x, c2.y, c2.z, c2.w, 2, 240, 180, 16);
        int l3 = lin_scale(c3.x, c3.y, c3.z, c3.w, 2, 240, 180, 16);
        int rk0 = rankArr[l0], rk1 = rankArr[l1];
        int rk2 = rankArr[l2], rk3 = rankArr[l3];

        float x0 = red[(size_t)s0 * CR + lane];
        float x1 = red[(size_t)s1 * CR + lane];
        float x2 = red[(size_t)s2 * CR + lane];
        float x3 = red[(size_t)s3 * CR + lane];
        float h0 = gc[(size_t)rk0 * CR + lane];
        float h1 = gc[(size_t)rk1 * CR + lane];
        float h2 = gc[(size_t)rk2 * CR + lane];
        float h3 = gc[(size_t)rk3 * CR + lane];
#pragma unroll
        for (int k = 0; k < CR; ++k) {
            float w = s_W1[k * CR + lane];
            h0 += bcastf(x0, k) * w;
            h1 += bcastf(x1, k) * w;
            h2 += bcastf(x2, k) * w;
            h3 += bcastf(x3, k) * w;
        }
        h0 = fmaxf(h0, 0.f); h1 = fmaxf(h1, 0.f);
        h2 = fmaxf(h2, 0.f); h3 = fmaxf(h3, 0.f);

        float q0 = lob, q1 = lob, q2 = lob, q3 = lob;
#pragma unroll
        for (int k = 0; k < CR; ++k) {
            float w = s_W2[k * CR + lane];
            q0 += bcastf(h0, k) * w;
            q1 += bcastf(h1, k) * w;
            q2 += bcastf(h2, k) * w;
            q3 += bcastf(h3, k) * w;
        }
        outProj[(size_t)i0 * CR + lane] = q0;
        outProj[(size_t)i1 * CR + lane] = q1;
        outProj[(size_t)i2 * CR + lane] = q2;
        outProj[(size_t)i3 * CR + lane] = q3;

        // fused scatter-max
        int4 b0 = ((const int4*)bxyz)[i0];
        int4 b1 = ((const int4*)bxyz)[i1];
        int4 b2 = ((const int4*)bxyz)[i2];
        int4 b3 = ((const int4*)bxyz)[i3];
        int n0 = ((b0.x * GZ2 + b0.w) * GY2 + b0.z) * GX2 + b0.y;
        int n1 = ((b1.x * GZ2 + b1.w) * GY2 + b1.z) * GX2 + b1.y;
        int n2 = ((b2.x * GZ2 + b2.w) * GY2 + b2.z) * GX2 + b2.y;
        int n3 = ((b3.x * GZ2 + b3.w) * GY2 + b3.z) * GX2 + b3.y;
        if (lane == 0) {
            outLin[i0] = (float)n0; flags[n0] = 1;
            outLin[i1] = (float)n1; flags[n1] = 1;
            outLin[i2] = (float)n2; flags[n2] = 1;
            outLin[i3] = (float)n3; flags[n3] = 1;
        }
        atomicMax(&tvKey[(size_t)n0 * CR + lane], fkey(q0));
        atomicMax(&tvKey[(size_t)n1 * CR + lane], fkey(q1));
        atomicMax(&tvKey[(size_t)n2 * CR + lane], fkey(q2));
        atomicMax(&tvKey[(size_t)n3 * CR + lane], fkey(q3));
    }
}

// ---------------- K5: decode tv keys, flag-driven ----------------
__global__ __launch_bounds__(256) void k_fix(
        unsigned int* __restrict__ tv, const unsigned char* __restrict__ flags) {
    int lane = threadIdx.x & 63;
    int wid = blockIdx.x * 4 + (threadIdx.x >> 6);
    int nw  = gridDim.x * 4;
    for (int batch = wid; batch < NBATCH; batch += nw) {
        int base = batch * 64;
        unsigned char f = flags[base + lane];
        unsigned long long mask = __ballot(f != 0);
        while (mask) {
            int j = __ffsll((long long)mask) - 1; mask &= mask - 1;
            size_t idx = (size_t)(base + j) * CR + lane;
            unsigned int k = tv[idx];
            float v = (k == 0u) ? 0.f
                    : __uint_as_float((k & 0x80000000u) ? (k & 0x7FFFFFFFu) : ~k);
            ((float*)tv)[idx] = v;
        }
    }
}

extern "C" void kernel_launch(void* const* d_in, const int* in_sizes, int n_in,
                              void* d_out, int out_size, void* d_ws, size_t ws_size,
                              hipStream_t stream) {
    (void)in_sizes; (void)n_in; (void)out_size; (void)ws_size;
    const float* in_data = (const float*)d_in[0];
    const int*   coords  = (const int*)d_in[1];
    const int*   inv     = (const int*)d_in[2];
    const int*   bxyz    = (const int*)d_in[3];
    const float* W_red   = (const float*)d_in[4];
    const float* b_red   = (const float*)d_in[5];
    const float* fcW     = (const float*)d_in[6];
    const float* fcB     = (const float*)d_in[7];
    const float* fcsW    = (const float*)d_in[8];
    const float* fcsB    = (const float*)d_in[9];
    const float* fc_W    = (const float*)d_in[10];
    const float* outW    = (const float*)d_in[11];
    const float* loW1    = (const float*)d_in[12];
    const float* loW2    = (const float*)d_in[13];
    const float* lob2    = (const float*)d_in[14];

    float* outProj = (float*)d_out;
    float* tv      = outProj + (size_t)NPTS * CR;        // tv region (sum0 -> keys -> tv_fmap)
    float* outLin  = tv + (size_t)TVSEG * CR;

    float* ws_f   = (float*)d_ws;
    float* red    = ws_f;                                // NPTS*64           (51.2 MB)
    float* attbuf = red + (size_t)NPTS * CR;             // 252000*32         (32.3 MB)
    float* cnt    = attbuf + (size_t)SUM123_ROWS * CR2;  // NSEG0 floats ----+ one memset
    int*   listCount = (int*)(cnt + (size_t)NSEG0);      // 4 ints           |
    unsigned char* flags = (unsigned char*)(listCount + 4); // TVSEG bytes --+
    int*   rankArr   = (int*)(flags + (size_t)TVSEG);    // NSEG0 ints
    int*   list0     = rankArr + (size_t)NSEG0;          // NPTS ints
    float* gc     = (float*)(list0 + (size_t)NPTS);      // NPTS*64           (51.2 MB)
    float* Mmat   = gc + (size_t)NPTS * CR;              // 2048

    hipMemsetAsync(tv, 0, (size_t)TVSEG * CR * sizeof(float), stream);
    hipMemsetAsync(cnt, 0, (size_t)NSEG0 * 4 + 16 + (size_t)TVSEG, stream);

    k_redscat<<<2048, 256, 0, stream>>>(in_data, coords, W_red, b_red,
                                        red, tv, cnt);
    k_buildlist<<<278, 256, 0, stream>>>(cnt, list0, listCount, rankArr,
                                         outW, loW1, Mmat);
    k_gatt<<<2048, 256, 0, stream>>>(tv, attbuf, cnt, fcW, fcB);
    k_segf<<<1024, 256, 0, stream>>>(tv, cnt, list0, (const int*)listCount,
                                     fcW, fcB, fc_W, fcsW, fcsB, Mmat,
                                     attbuf, gc);
    k_pgmax<<<2048, 256, 0, stream>>>(red, gc, rankArr, coords, inv, bxyz,
                                      loW1, loW2, lob2, outProj,
                                      outLin, (unsigned int*)tv, flags);
    k_fix<<<1024, 256, 0, stream>>>((unsigned int*)tv, flags);
}